// Round 6
// baseline (4269.021 us; speedup 1.0000x reference)
//
#include <hip/hip_runtime.h>

// ---------------- constants ----------------
#define T_LEN 512
#define BATCH 32
#define HDIR  256
#define KTAG  24
#define START_TAG 22
#define STOP_TAG  23
#define NEGV  (-10000.0f)
#define SENTU 0x7FC0DEADu   // NaN payload; h can never be NaN (sig*tanh)

typedef float vf4 __attribute__((ext_vector_type(4)));

// workspace layout (float elements) -- identical to the verified baseline.
#define XPROJ_OFF   0ull
#define XPROJ_ELEMS (2ull*512*1024*32)            // [dir][t][row1024][b32]
#define FEATS_OFF   (XPROJ_OFF + XPROJ_ELEMS)     // [t][b][24]
#define FEATS_ELEMS (512ull*32*24)
#define HIST_OFF    (FEATS_OFF + FEATS_ELEMS)     // [dir][slot513][bh8][j256][bl4]
#define HIST_ELEMS  (2ull*513*8192)
// xproj tile flags live in hist[dir0][slot0][0..2047] (slot 0 is never used for
// data; it is sentinel-poisoned by k_fill each launch). flag(dir,mt,y) at
// hist[dir*1024 + mt*8 + y]; GEMM writes 0.0f after its tile is in MALL.

// lgkm-only barrier: LDS producer/consumer sync WITHOUT draining vmcnt --
// publish stores and xproj prefetch loads stay in flight across it.
#define BARRIER_LGKM() asm volatile("s_waitcnt lgkmcnt(0)\n\ts_barrier" ::: "memory")

__device__ __forceinline__ float fsig(float x) {
  return __builtin_amdgcn_rcpf(1.0f + __expf(-x));
}
__device__ __forceinline__ float ftanh(float x) {
  return 2.0f * __builtin_amdgcn_rcpf(1.0f + __expf(-2.0f * x)) - 1.0f;
}
__device__ __forceinline__ unsigned um(unsigned a, unsigned b) { return a < b ? a : b; }

// ---------------- K1: sentinel-fill hist (direct to MALL via sc0 sc1) ----------------
__global__ void k_fill(float* __restrict__ p, int n4) {
  int i = blockIdx.x * blockDim.x + threadIdx.x;
  if (i < n4) {
    float* dst = p + (size_t)i * 4;
    const float sv = __uint_as_float(SENTU);
    vf4 v; v.x = sv; v.y = sv; v.z = sv; v.w = sv;
    asm volatile("global_store_dwordx4 %0, %1, off sc0 sc1"
                 :: "v"(dst), "v"(v) : "memory");
  }
}

// ---------------- K2 (fused): GEMM producer + BiLSTM + feats consumer ----------------
// Grid = 2624 blocks, in-order dispatch (structure verified in R5):
//   blocks 0..63     : LSTM; blocks 64..2111 : xproj GEMM; 2112..2623 : feats.
// LDS: 50176 B static + 32768 B dynamic ballast => 1 block/CU.
// R6 change (LSTM poll only): single-phase poll. All 8 chunk loads issued per
// iteration with chunk 7 FIRST; s_waitcnt vmcnt(7) retires (in issue order)
// everything older than chunks 0..6 -- i.e. chunk 7 plus any straggler stores
// -- while chunks 0..6 remain in flight. On detection the register-tied
// vmcnt(0) costs ~0 extra latency (0..6 were issued simultaneously with 7),
// removing the dependent phase-2 MALL round trip from every step's critical
// path. Fail path drains vmcnt before re-issue (WAW-safe).
__global__ __launch_bounds__(256, 1) void k_main(
    const int* __restrict__ sent, const float* __restrict__ emb,
    const float* __restrict__ wihf, const float* __restrict__ wihb,
    const float* __restrict__ bihf, const float* __restrict__ bhhf,
    const float* __restrict__ bihb, const float* __restrict__ bhhb,
    const float* __restrict__ whhf, const float* __restrict__ whhb,
    const float* __restrict__ h0, const float* __restrict__ c0,
    const float* __restrict__ wout, const float* __restrict__ bout,
    float* __restrict__ xproj, float* __restrict__ feats,
    float* __restrict__ hist)
{
  extern __shared__ float dynpad[];        // occupancy ballast (32 KB at launch)
  __shared__ float smem[12544];            // 50176 B, aliased per path
  const int bid = blockIdx.x;
  const int tid = threadIdx.x;
  if (sent == (const int*)0) dynpad[0] = 0.f;  // keep dynamic LDS alive; never taken

  if (bid >= 64 && bid < 2112) {
    // ================= xproj GEMM path (unchanged from R5) =================
    float (*As)[132] = (float (*)[132])(smem);          // 2112 f
    float (*Bs)[132] = (float (*)[132])(smem + 2112);   // 2112 f
    int* sid = (int*)(smem + 4224);                     // 128 ints
    const int idx = bid - 64;                // 0..2047
    const int mt_rank = idx >> 4;            // 0..127
    const int sub = idx & 15;                // (n-tile, dir)
    const int y = sub >> 1;                  // 0..7
    const int dir = sub & 1;
    const int mt = (mt_rank & 1) ? (127 - (mt_rank >> 1)) : (mt_rank >> 1);
    const int m0 = mt * 128;
    const int n0 = y * 128;
    const float* __restrict__ W = dir ? wihb : wihf;
    if (tid < 128) {
      int m = m0 + tid;                      // m = t*32 + b
      sid[tid] = sent[(m & 31) * 512 + (m >> 5)];
    }
    __syncthreads();
    float acc[8][8];
#pragma unroll
    for (int i = 0; i < 8; ++i)
#pragma unroll
      for (int j = 0; j < 8; ++j) acc[i][j] = 0.f;
    const int r = tid >> 1, qq = tid & 1;
    const int ty = tid >> 4, tx = tid & 15;
    const float* ap = &emb[(size_t)sid[r] * 256 + qq * 8];
    const float* bp = &W[(size_t)(n0 + r) * 256 + qq * 8];
    float4 a0 = *(const float4*)(ap);
    float4 a1 = *(const float4*)(ap + 4);
    float4 b0 = *(const float4*)(bp);
    float4 b1 = *(const float4*)(bp + 4);
    for (int k0 = 0; k0 < 256; k0 += 16) {
      __syncthreads();                       // previous tile's readers done
      As[qq*8+0][r] = a0.x; As[qq*8+1][r] = a0.y; As[qq*8+2][r] = a0.z; As[qq*8+3][r] = a0.w;
      As[qq*8+4][r] = a1.x; As[qq*8+5][r] = a1.y; As[qq*8+6][r] = a1.z; As[qq*8+7][r] = a1.w;
      Bs[qq*8+0][r] = b0.x; Bs[qq*8+1][r] = b0.y; Bs[qq*8+2][r] = b0.z; Bs[qq*8+3][r] = b0.w;
      Bs[qq*8+4][r] = b1.x; Bs[qq*8+5][r] = b1.y; Bs[qq*8+6][r] = b1.z; Bs[qq*8+7][r] = b1.w;
      __syncthreads();
      if (k0 + 16 < 256) {                   // prefetch next k-panel under compute
        const float* ap2 = ap + k0 + 16;
        const float* bp2 = bp + k0 + 16;
        a0 = *(const float4*)(ap2);
        a1 = *(const float4*)(ap2 + 4);
        b0 = *(const float4*)(bp2);
        b1 = *(const float4*)(bp2 + 4);
      }
#pragma unroll
      for (int kk = 0; kk < 16; ++kk) {
        float4 av0 = *(const float4*)&As[kk][ty*8];
        float4 av1 = *(const float4*)&As[kk][ty*8+4];
        float4 bv0 = *(const float4*)&Bs[kk][tx*8];
        float4 bv1 = *(const float4*)&Bs[kk][tx*8+4];
        float am[8] = {av0.x,av0.y,av0.z,av0.w,av1.x,av1.y,av1.z,av1.w};
        float bn[8] = {bv0.x,bv0.y,bv0.z,bv0.w,bv1.x,bv1.y,bv1.z,bv1.w};
#pragma unroll
        for (int i = 0; i < 8; ++i)
#pragma unroll
          for (int j = 0; j < 8; ++j)
            acc[i][j] = fmaf(am[i], bn[j], acc[i][j]);
      }
    }
    const float* bi_p = dir ? bihb : bihf;
    const float* bh_p = dir ? bhhb : bhhf;
    float bias[8];
#pragma unroll
    for (int j = 0; j < 8; ++j) { int n = n0 + tx*8 + j; bias[j] = bi_p[n] + bh_p[n]; }
    const int mb = m0 + ty * 8;
    const int tt = mb >> 5, bb = mb & 31;
#pragma unroll
    for (int j = 0; j < 8; ++j) {
      int n = n0 + tx*8 + j;
      float* dst = &xproj[((((size_t)dir*512 + tt)*1024) + n)*32 + bb];
      vf4 o0, o1;
      o0[0] = acc[0][j]+bias[j]; o0[1] = acc[1][j]+bias[j];
      o0[2] = acc[2][j]+bias[j]; o0[3] = acc[3][j]+bias[j];
      o1[0] = acc[4][j]+bias[j]; o1[1] = acc[5][j]+bias[j];
      o1[2] = acc[6][j]+bias[j]; o1[3] = acc[7][j]+bias[j];
      asm volatile(
        "global_store_dwordx4 %0, %2, off sc0 sc1\n\t"
        "global_store_dwordx4 %1, %3, off sc0 sc1"
        :: "v"(dst), "v"(dst + 4), "v"(o0), "v"(o1) : "memory");
    }
    asm volatile("s_waitcnt vmcnt(0)" ::: "memory");
    __syncthreads();
    if (tid == 0) {
      float* fp = hist + (size_t)dir * 1024 + (size_t)mt * 8 + y;
      const float z = 0.f;
      asm volatile("global_store_dword %0, %1, off sc0 sc1"
                   :: "v"(fp), "v"(z) : "memory");
    }
    return;
  }

  if (bid >= 2112) {
    // ================= feats path (unchanged from R5) =================
    const int f = bid - 2112;                 // 0..511
    const int t = (f & 1) ? (256 + (f >> 1)) : (255 - (f >> 1));
    float* hlds = smem;                       // [32][258] per pass (8256 f)
    const float* sF = hist + ((size_t)0*513 + (t + 1)) * 8192;
    const float* sB = hist + ((size_t)1*513 + (512 - t)) * 8192;
    {
      const int p = tid & 31;
      const float* pp = (((tid >> 5) & 1) ? sB : sF) + 32 * p;
      while (true) {
        float v;
        asm volatile("global_load_dword %0, %1, off sc0 sc1\n\ts_waitcnt vmcnt(0)"
                     : "=&v"(v) : "v"(pp) : "memory");
        int bad = (__float_as_uint(v) == SENTU) ? 1 : 0;
        if (!__any(bad)) break;
        __builtin_amdgcn_s_sleep(64);
      }
    }
    const int b = tid >> 3, ks = tid & 7;
    float accv[3];
    for (int dir2 = 0; dir2 < 2; ++dir2) {
      const float* sp = (dir2 ? sB : sF) + (size_t)tid * 4;
      vf4 v[8];
      while (true) {                          // bulk load + full verify
        asm volatile(
          "global_load_dwordx4 %0, %8, off sc0 sc1\n\t"
          "global_load_dwordx4 %1, %9, off sc0 sc1\n\t"
          "global_load_dwordx4 %2, %10, off sc0 sc1\n\t"
          "global_load_dwordx4 %3, %11, off sc0 sc1\n\t"
          "global_load_dwordx4 %4, %12, off sc0 sc1\n\t"
          "global_load_dwordx4 %5, %13, off sc0 sc1\n\t"
          "global_load_dwordx4 %6, %14, off sc0 sc1\n\t"
          "global_load_dwordx4 %7, %15, off sc0 sc1\n\t"
          "s_waitcnt vmcnt(0)"
          : "=&v"(v[0]), "=&v"(v[1]), "=&v"(v[2]), "=&v"(v[3]),
            "=&v"(v[4]), "=&v"(v[5]), "=&v"(v[6]), "=&v"(v[7])
          : "v"(sp), "v"(sp+1024), "v"(sp+2048), "v"(sp+3072),
            "v"(sp+4096), "v"(sp+5120), "v"(sp+6144), "v"(sp+7168)
          : "memory");
        unsigned z = 0xFFFFFFFFu;
#pragma unroll
        for (int q = 0; q < 8; ++q)
#pragma unroll
          for (int bl = 0; bl < 4; ++bl)
            z = um(z, __float_as_uint(v[q][bl]) ^ SENTU);
        if (z) break;
        __builtin_amdgcn_s_sleep(16);
      }
#pragma unroll
      for (int q = 0; q < 8; ++q)
#pragma unroll
        for (int bl = 0; bl < 4; ++bl)
          hlds[(4*q + bl)*258 + tid] = v[q][bl];   // row b=4q+bl, col j=tid
      __syncthreads();
#pragma unroll
      for (int kt = 0; kt < 3; ++kt) {
        const int k = kt * 8 + ks;
        if (dir2 == 0) accv[kt] = bout[k];
        const float* wr = wout + (size_t)k * 512 + dir2 * 256;
        float a = accv[kt];
#pragma unroll 8
        for (int kk = 0; kk < 256; kk += 4) {
          float4 h4 = *(const float4*)&hlds[b * 258 + kk];
          float4 w4 = *(const float4*)&wr[kk];
          a += h4.x*w4.x + h4.y*w4.y + h4.z*w4.z + h4.w*w4.w;
        }
        accv[kt] = a;
      }
      __syncthreads();                        // before pass-2 overwrites hlds
    }
#pragma unroll
    for (int kt = 0; kt < 3; ++kt)
      feats[((size_t)t * 32 + b) * 24 + kt * 8 + ks] = accv[kt];
    return;
  }

  // ================= LSTM path =================
  float* hl = smem + 4352;                   // 8192 f
  const int dir = bid >> 5;
  const int slice = bid & 31;
  const int rowg = tid >> 5;           // 0..7 => j_local
  const int bgrp = (tid >> 3) & 3;     // 0..3
  const int kgrp = tid & 7;            // 0..7
  const int jg = slice * 8 + rowg;     // 0..255
  const float* __restrict__ W = dir ? whhb : whhf;

  // weights -> registers: w2[gate][kk2] covers k = kgrp*32 + 2*kk2 (+1)
  float2 w2[4][16];
#pragma unroll
  for (int g = 0; g < 4; ++g)
#pragma unroll
    for (int kk2 = 0; kk2 < 16; ++kk2)
      w2[g][kk2] = *(const float2*)&W[(size_t)(g*256 + jg)*256 + kgrp*32 + 2*kk2];

  // cell state (redundant across kgrp lanes)
  float cc[8];
#pragma unroll
  for (int bi = 0; bi < 8; ++bi)
    cc[bi] = c0[(size_t)(dir*32 + bgrp*8 + bi)*256 + jg];

  const int kk = tid & 31;
  const int base_col = tid & ~31;
  const int kw4 = 4*((tid >> 5) & 7);
  const int rot = (4*kgrp + 2*bgrp) & 31;
  float* const histd = hist + (size_t)dir * 513 * 8192;
  float hnew[8];

  for (int s = 0; s < 512; ++s) {
    const int t = dir ? (511 - s) : s;

    // (a) obtain h input: column j = tid, all 32 b.
    // Single-phase poll: issue ch7 FIRST then ch0..6; vmcnt(7) waits (in-order
    // retirement) for everything older than ch0..6 -- i.e. ch7 + any straggler
    // publish stores (conservative, always correct). On detect, the tied
    // vmcnt(0) retires ch0..6 whose latency fully overlapped ch7's.
    vf4 hv[8];
    if (s == 0) {
#pragma unroll
      for (int q = 0; q < 8; ++q)
#pragma unroll
        for (int bl = 0; bl < 4; ++bl)
          hv[q][bl] = h0[(size_t)(dir*32 + 4*q + bl)*256 + tid];
    } else {
      const float* sp = histd + (size_t)s*8192 + (size_t)tid*4;
      const float* p0 = sp;
      const float* p1 = sp + 1024;
      const float* p2 = sp + 2048;
      const float* p3 = sp + 3072;
      const float* p4 = sp + 4096;
      const float* p5 = sp + 5120;
      const float* p6 = sp + 6144;
      const float* p7 = sp + 7168;
      while (true) {
        asm volatile(
          "global_load_dwordx4 %0, %8, off sc0 sc1\n\t"   // ch7 first (oldest)
          "global_load_dwordx4 %1, %9, off sc0 sc1\n\t"
          "global_load_dwordx4 %2, %10, off sc0 sc1\n\t"
          "global_load_dwordx4 %3, %11, off sc0 sc1\n\t"
          "global_load_dwordx4 %4, %12, off sc0 sc1\n\t"
          "global_load_dwordx4 %5, %13, off sc0 sc1\n\t"
          "global_load_dwordx4 %6, %14, off sc0 sc1\n\t"
          "global_load_dwordx4 %7, %15, off sc0 sc1\n\t"
          "s_waitcnt vmcnt(7)"
          : "=&v"(hv[7]), "=&v"(hv[0]), "=&v"(hv[1]), "=&v"(hv[2]),
            "=&v"(hv[3]), "=&v"(hv[4]), "=&v"(hv[5]), "=&v"(hv[6])
          : "v"(p7), "v"(p0), "v"(p1), "v"(p2),
            "v"(p3), "v"(p4), "v"(p5), "v"(p6)
          : "memory");
        unsigned z7 = 0xFFFFFFFFu;
#pragma unroll
        for (int bl = 0; bl < 4; ++bl)
          z7 = um(z7, __float_as_uint(hv[7][bl]) ^ SENTU);
        if (z7) {
          // detection: retire ch0..6 (latency already overlapped), verify
          asm volatile("s_waitcnt vmcnt(0)"
                       : "+v"(hv[0]), "+v"(hv[1]), "+v"(hv[2]), "+v"(hv[3]),
                         "+v"(hv[4]), "+v"(hv[5]), "+v"(hv[6])
                       :: "memory");
          unsigned z = 0xFFFFFFFFu;
#pragma unroll
          for (int q = 0; q < 7; ++q)
#pragma unroll
            for (int bl = 0; bl < 4; ++bl)
              z = um(z, __float_as_uint(hv[q][bl]) ^ SENTU);
          if (z) break;                       // all 32 words real => done
          // rare straggler in ch0..6: vmcnt already 0, sleep and re-issue
        } else {
          // ch7 still sentinel: drain in-flight ch0..6 before re-issue (WAW)
          asm volatile("s_waitcnt vmcnt(0)" ::: "memory");
        }
        __builtin_amdgcn_s_sleep(1);
      }
    }

    // (b) flag-gate (once per 4 steps) + xproj prefetch for THIS step, issued
    // AFTER the poll so the poll's waits never drain it; consumed after the
    // FMA block (~1.2us cover). Plain cached loads (flag => MALL truth).
    float xpr[4][8];
    if (kgrp == 0) {
      if ((t & 3) == (dir ? 3 : 0)) {
        const float* fp = hist + (size_t)dir*1024 + (size_t)(t >> 2)*8;
        while (true) {
          vf4 f0, f1;
          asm volatile(
            "global_load_dwordx4 %0, %2, off sc0 sc1\n\t"
            "global_load_dwordx4 %1, %3, off sc0 sc1\n\t"
            "s_waitcnt vmcnt(0)"
            : "=&v"(f0), "=&v"(f1) : "v"(fp), "v"(fp + 4) : "memory");
          unsigned bad = 0u;
#pragma unroll
          for (int l = 0; l < 4; ++l) {
            bad |= (__float_as_uint(f0[l]) == SENTU) ? 1u : 0u;
            bad |= (__float_as_uint(f1[l]) == SENTU) ? 1u : 0u;
          }
          if (!bad) break;
          __builtin_amdgcn_s_sleep(2);
        }
      }
#pragma unroll
      for (int g = 0; g < 4; ++g) {
        const float* xp = &xproj[((((size_t)dir*512 + t)*1024) + g*256 + jg)*32 + bgrp*8];
        float4 x0 = *(const float4*)xp;
        float4 x1 = *(const float4*)(xp + 4);
        xpr[g][0]=x0.x; xpr[g][1]=x0.y; xpr[g][2]=x0.z; xpr[g][3]=x0.w;
        xpr[g][4]=x1.x; xpr[g][5]=x1.y; xpr[g][6]=x1.z; xpr[g][7]=x1.w;
      }
    }

    // (c) scatter to LDS with rotation swizzle (identical hl contents as verified)
#pragma unroll
    for (int q = 0; q < 8; ++q) {
      const int rwq = (kw4 + 2*((q >> 1) & 3)) & 31;
      const int col = base_col + ((kk + rwq) & 31);
#pragma unroll
      for (int bl = 0; bl < 4; ++bl)
        hl[(4*q + bl)*256 + col] = hv[q][bl];
    }
    BARRIER_LGKM();

    // (d) gates partial sums over our 32-k slice
    float acc[4][8];
#pragma unroll
    for (int g = 0; g < 4; ++g)
#pragma unroll
      for (int bi = 0; bi < 8; ++bi) acc[g][bi] = 0.f;

    const int hbase = kgrp * 32;
#pragma unroll
    for (int kk2 = 0; kk2 < 16; ++kk2) {
      const int idx = hbase + ((2*kk2 + rot) & 31);
      float2 h2[8];
#pragma unroll
      for (int bi = 0; bi < 8; ++bi)
        h2[bi] = *(const float2*)&hl[(bgrp*8 + bi)*256 + idx];
#pragma unroll
      for (int g = 0; g < 4; ++g)
#pragma unroll
        for (int bi = 0; bi < 8; ++bi) {
          acc[g][bi] = fmaf(w2[g][kk2].x, h2[bi].x, acc[g][bi]);
          acc[g][bi] = fmaf(w2[g][kk2].y, h2[bi].y, acc[g][bi]);
        }
    }

    // (e) xproj term once (kgrp==0), then butterfly-reduce over the 8 kgrp lanes
    if (kgrp == 0) {
#pragma unroll
      for (int g = 0; g < 4; ++g)
#pragma unroll
        for (int bi = 0; bi < 8; ++bi) acc[g][bi] += xpr[g][bi];
    }
#pragma unroll
    for (int g = 0; g < 4; ++g)
#pragma unroll
      for (int bi = 0; bi < 8; ++bi) {
        float v = acc[g][bi];
        v += __shfl_xor(v, 1, 64);
        v += __shfl_xor(v, 2, 64);
        v += __shfl_xor(v, 4, 64);
        acc[g][bi] = v;
      }

    // (f) LSTM cell update (PyTorch gate order i,f,g,o)
#pragma unroll
    for (int bi = 0; bi < 8; ++bi) {
      float ig = fsig(acc[0][bi]);
      float fg = fsig(acc[1][bi]);
      float gg = ftanh(acc[2][bi]);
      float og = fsig(acc[3][bi]);
      cc[bi] = fg * cc[bi] + ig * gg;
      hnew[bi] = og * ftanh(cc[bi]);
    }

    // (g) publish h into slot s+1 immediately (fire & forget; rides across the
    // barrier below; next poll's waits retire it before hnew is rewritten)
    if (kgrp == 0) {
      float* dp  = histd + (size_t)(s + 1)*8192 + ((size_t)(2*bgrp)*256 + jg)*4;
      float* dp2 = dp + 1024;
      vf4 s0; s0.x = hnew[0]; s0.y = hnew[1]; s0.z = hnew[2]; s0.w = hnew[3];
      vf4 s1; s1.x = hnew[4]; s1.y = hnew[5]; s1.z = hnew[6]; s1.w = hnew[7];
      asm volatile(
        "global_store_dwordx4 %0, %2, off sc0 sc1\n\t"
        "global_store_dwordx4 %1, %3, off sc0 sc1"
        :: "v"(dp), "v"(dp2), "v"(s0), "v"(s1) : "memory");
    }

    BARRIER_LGKM();   // protect hl before next scatter (no vmcnt drain)
  }
}

// ---------------- K5: Viterbi + backtrace, one wave per batch element ----------------
// R6: the 24-way first-max is split into 4 independent 6-chains merged with
// strict-> (earlier chain wins ties) -- provably identical to sequential
// first-max/lowest-index semantics, ~4x shorter dependency chain per step.
__global__ __launch_bounds__(64) void k_viterbi(
    const float* __restrict__ feats, const float* __restrict__ trans,
    float* __restrict__ out)
{
  const int b = blockIdx.x;      // 0..31
  const int lane = threadIdx.x;  // 0..63 ; active tag lane if <24
  const int k = lane;
  __shared__ float fvl[2][32];
  __shared__ float pathb[512];
  __shared__ unsigned char bcol[512 * 24];
  float trr[24];
  if (k < 24) {
#pragma unroll
    for (int pv = 0; pv < 24; ++pv) trr[pv] = trans[k * 24 + pv];
  }
  if (k < 32) fvl[0][k] = (k == START_TAG) ? 0.f : NEGV;
  if (k < 32) fvl[1][k] = NEGV;
  __syncthreads();
  float fcur = (k < 24) ? feats[b * 24 + k] : 0.f;
  int q = 0;
  for (int t = 0; t < 512; ++t) {
    float fnext = (t < 511 && k < 24) ? feats[(size_t)(t + 1) * 768 + b * 24 + k] : 0.f;
    float fvp[24];
    {
      const float4* fp4 = (const float4*)&fvl[q][0];
#pragma unroll
      for (int i = 0; i < 6; ++i) {
        float4 v = fp4[i];
        fvp[i*4+0] = v.x; fvp[i*4+1] = v.y; fvp[i*4+2] = v.z; fvp[i*4+3] = v.w;
      }
    }
    // 4 independent 6-chains (ILP), merge earlier-chain-wins-ties
    float c0v = -3.4e38f, c1v = -3.4e38f, c2v = -3.4e38f, c3v = -3.4e38f;
    int   c0i = 0, c1i = 6, c2i = 12, c3i = 18;
#pragma unroll
    for (int j = 0; j < 6; ++j) {
      float v0 = fvp[j]      + trr[j];
      float v1 = fvp[6 + j]  + trr[6 + j];
      float v2 = fvp[12 + j] + trr[12 + j];
      float v3 = fvp[18 + j] + trr[18 + j];
      if (v0 > c0v) { c0v = v0; c0i = j; }
      if (v1 > c1v) { c1v = v1; c1i = 6 + j; }
      if (v2 > c2v) { c2v = v2; c2i = 12 + j; }
      if (v3 > c3v) { c3v = v3; c3i = 18 + j; }
    }
    if (c1v > c0v) { c0v = c1v; c0i = c1i; }
    if (c3v > c2v) { c2v = c3v; c2i = c3i; }
    float best = c0v; int bp = c0i;
    if (c2v > best) { best = c2v; bp = c2i; }
    if (k < 24) {
      fvl[q ^ 1][k] = best + fcur;
      bcol[t * 24 + k] = (unsigned char)bp;
    }
    fcur = fnext;
    q ^= 1;
    __syncthreads();
  }
  if (lane == 0) {
    float best = -3.4e38f; int bt = 0;
#pragma unroll
    for (int kk = 0; kk < 24; ++kk) {
      float v = fvl[q][kk] + trans[STOP_TAG * 24 + kk];
      if (v > best) { best = v; bt = kk; }
    }
    out[b] = best;
    pathb[511] = (float)bt;
    int tag = bt;
    for (int t = 511; t >= 1; --t) {
      tag = bcol[t * 24 + tag];
      pathb[t - 1] = (float)tag;
    }
  }
  __syncthreads();
#pragma unroll
  for (int it = 0; it < 8; ++it)
    out[32 + (size_t)b * 512 + it * 64 + lane] = pathb[it * 64 + lane];
}

// ---------------- launch ----------------
extern "C" void kernel_launch(void* const* d_in, const int* in_sizes, int n_in,
                              void* d_out, int out_size, void* d_ws, size_t ws_size,
                              hipStream_t stream) {
  (void)in_sizes; (void)n_in; (void)out_size; (void)ws_size;
  const int*   sent = (const int*)d_in[0];
  const float* emb  = (const float*)d_in[1];
  const float* wihf = (const float*)d_in[2];
  const float* whhf = (const float*)d_in[3];
  const float* bihf = (const float*)d_in[4];
  const float* bhhf = (const float*)d_in[5];
  const float* wihb = (const float*)d_in[6];
  const float* whhb = (const float*)d_in[7];
  const float* bihb = (const float*)d_in[8];
  const float* bhhb = (const float*)d_in[9];
  const float* wout = (const float*)d_in[10];
  const float* bout = (const float*)d_in[11];
  const float* trans= (const float*)d_in[12];
  const float* h0   = (const float*)d_in[13];
  const float* c0   = (const float*)d_in[14];

  float* ws     = (float*)d_ws;
  float* xproj  = ws + XPROJ_OFF;
  float* feats  = ws + FEATS_OFF;
  float* hist   = ws + HIST_OFF;

  // sentinel-fill hist only (67 MB; includes slot-0 flag region of both dirs)
  const int n4 = (int)(HIST_ELEMS / 4);
  k_fill<<<(n4 + 255) / 256, 256, 0, stream>>>(hist, n4);
  // fused dispatch: 64 LSTM blocks (resident first), 2048 GEMM blocks,
  // 512 feats blocks (dispatched last, center-out readiness order).
  k_main<<<2624, 256, 32768, stream>>>(sent, emb, wihf, wihb,
                                       bihf, bhhf, bihb, bhhb,
                                       whhf, whhb, h0, c0,
                                       wout, bout, xproj, feats, hist);
  k_viterbi<<<32, 64, 0, stream>>>(feats, trans, (float*)d_out);
}

// Round 7
// 4094.283 us; speedup vs baseline: 1.0427x; 1.0427x over previous
//
#include <hip/hip_runtime.h>

// ---------------- constants ----------------
#define T_LEN 512
#define BATCH 32
#define HDIR  256
#define KTAG  24
#define START_TAG 22
#define STOP_TAG  23
#define NEGV  (-10000.0f)
#define SENTU 0x7FC0DEADu   // NaN payload; h can never be NaN (sig*tanh)

typedef float vf4 __attribute__((ext_vector_type(4)));

// workspace layout (float elements) -- identical to the verified baseline.
#define XPROJ_OFF   0ull
#define XPROJ_ELEMS (2ull*512*1024*32)            // [dir][t][row1024][b32]
#define FEATS_OFF   (XPROJ_OFF + XPROJ_ELEMS)     // [t][b][24]
#define FEATS_ELEMS (512ull*32*24)
#define HIST_OFF    (FEATS_OFF + FEATS_ELEMS)     // [dir][slot513][bh8][j256][bl4]
#define HIST_ELEMS  (2ull*513*8192)
// xproj tile flags live in hist[dir0][slot0][0..2047] (slot 0 is never used for
// data; it is sentinel-poisoned by k_fill each launch). flag(dir,mt,y) at
// hist[dir*1024 + mt*8 + y]; GEMM writes 0.0f after its tile is in MALL.

// lgkm-only barrier: LDS producer/consumer sync WITHOUT draining vmcnt --
// publish stores and xproj prefetch loads stay in flight across it.
#define BARRIER_LGKM() asm volatile("s_waitcnt lgkmcnt(0)\n\ts_barrier" ::: "memory")

__device__ __forceinline__ float fsig(float x) {
  return __builtin_amdgcn_rcpf(1.0f + __expf(-x));
}
__device__ __forceinline__ float ftanh(float x) {
  return 2.0f * __builtin_amdgcn_rcpf(1.0f + __expf(-2.0f * x)) - 1.0f;
}
__device__ __forceinline__ unsigned um(unsigned a, unsigned b) { return a < b ? a : b; }
__device__ __forceinline__ float rdlane(float v, int l) {
  return __uint_as_float((unsigned)__builtin_amdgcn_readlane((int)__float_as_uint(v), l));
}

// ---------------- K1: sentinel-fill hist (direct to MALL via sc0 sc1) ----------------
__global__ void k_fill(float* __restrict__ p, int n4) {
  int i = blockIdx.x * blockDim.x + threadIdx.x;
  if (i < n4) {
    float* dst = p + (size_t)i * 4;
    const float sv = __uint_as_float(SENTU);
    vf4 v; v.x = sv; v.y = sv; v.z = sv; v.w = sv;
    asm volatile("global_store_dwordx4 %0, %1, off sc0 sc1"
                 :: "v"(dst), "v"(v) : "memory");
  }
}

// ---------------- K2 (fused): GEMM producer + BiLSTM + feats consumer ----------------
// Grid = 2624 blocks, in-order dispatch (R5-verified structure, reverted from R6):
//   blocks 0..63     : LSTM; blocks 64..2111 : xproj GEMM; 2112..2623 : feats.
// LDS: 50176 B static + 32768 B dynamic ballast => 1 block/CU.
// Poll discipline (R6 lesson): spin with the SMALLEST footprint (1 chunk);
// pay the bulk 7-chunk RT once after detection. Heavier spins congest MALL.
__global__ __launch_bounds__(256, 1) void k_main(
    const int* __restrict__ sent, const float* __restrict__ emb,
    const float* __restrict__ wihf, const float* __restrict__ wihb,
    const float* __restrict__ bihf, const float* __restrict__ bhhf,
    const float* __restrict__ bihb, const float* __restrict__ bhhb,
    const float* __restrict__ whhf, const float* __restrict__ whhb,
    const float* __restrict__ h0, const float* __restrict__ c0,
    const float* __restrict__ wout, const float* __restrict__ bout,
    float* __restrict__ xproj, float* __restrict__ feats,
    float* __restrict__ hist)
{
  extern __shared__ float dynpad[];        // occupancy ballast (32 KB at launch)
  __shared__ float smem[12544];            // 50176 B, aliased per path
  const int bid = blockIdx.x;
  const int tid = threadIdx.x;
  if (sent == (const int*)0) dynpad[0] = 0.f;  // keep dynamic LDS alive; never taken

  if (bid >= 64 && bid < 2112) {
    // ================= xproj GEMM path =================
    float (*As)[132] = (float (*)[132])(smem);          // 2112 f
    float (*Bs)[132] = (float (*)[132])(smem + 2112);   // 2112 f
    int* sid = (int*)(smem + 4224);                     // 128 ints
    const int idx = bid - 64;                // 0..2047
    const int mt_rank = idx >> 4;            // 0..127
    const int sub = idx & 15;                // (n-tile, dir)
    const int y = sub >> 1;                  // 0..7
    const int dir = sub & 1;
    const int mt = (mt_rank & 1) ? (127 - (mt_rank >> 1)) : (mt_rank >> 1);
    const int m0 = mt * 128;
    const int n0 = y * 128;
    const float* __restrict__ W = dir ? wihb : wihf;
    if (tid < 128) {
      int m = m0 + tid;                      // m = t*32 + b
      sid[tid] = sent[(m & 31) * 512 + (m >> 5)];
    }
    __syncthreads();
    float acc[8][8];
#pragma unroll
    for (int i = 0; i < 8; ++i)
#pragma unroll
      for (int j = 0; j < 8; ++j) acc[i][j] = 0.f;
    const int r = tid >> 1, qq = tid & 1;
    const int ty = tid >> 4, tx = tid & 15;
    const float* ap = &emb[(size_t)sid[r] * 256 + qq * 8];
    const float* bp = &W[(size_t)(n0 + r) * 256 + qq * 8];
    float4 a0 = *(const float4*)(ap);
    float4 a1 = *(const float4*)(ap + 4);
    float4 b0 = *(const float4*)(bp);
    float4 b1 = *(const float4*)(bp + 4);
    for (int k0 = 0; k0 < 256; k0 += 16) {
      __syncthreads();                       // previous tile's readers done
      As[qq*8+0][r] = a0.x; As[qq*8+1][r] = a0.y; As[qq*8+2][r] = a0.z; As[qq*8+3][r] = a0.w;
      As[qq*8+4][r] = a1.x; As[qq*8+5][r] = a1.y; As[qq*8+6][r] = a1.z; As[qq*8+7][r] = a1.w;
      Bs[qq*8+0][r] = b0.x; Bs[qq*8+1][r] = b0.y; Bs[qq*8+2][r] = b0.z; Bs[qq*8+3][r] = b0.w;
      Bs[qq*8+4][r] = b1.x; Bs[qq*8+5][r] = b1.y; Bs[qq*8+6][r] = b1.z; Bs[qq*8+7][r] = b1.w;
      __syncthreads();
      if (k0 + 16 < 256) {                   // prefetch next k-panel under compute
        const float* ap2 = ap + k0 + 16;
        const float* bp2 = bp + k0 + 16;
        a0 = *(const float4*)(ap2);
        a1 = *(const float4*)(ap2 + 4);
        b0 = *(const float4*)(bp2);
        b1 = *(const float4*)(bp2 + 4);
      }
#pragma unroll
      for (int kk = 0; kk < 16; ++kk) {
        float4 av0 = *(const float4*)&As[kk][ty*8];
        float4 av1 = *(const float4*)&As[kk][ty*8+4];
        float4 bv0 = *(const float4*)&Bs[kk][tx*8];
        float4 bv1 = *(const float4*)&Bs[kk][tx*8+4];
        float am[8] = {av0.x,av0.y,av0.z,av0.w,av1.x,av1.y,av1.z,av1.w};
        float bn[8] = {bv0.x,bv0.y,bv0.z,bv0.w,bv1.x,bv1.y,bv1.z,bv1.w};
#pragma unroll
        for (int i = 0; i < 8; ++i)
#pragma unroll
          for (int j = 0; j < 8; ++j)
            acc[i][j] = fmaf(am[i], bn[j], acc[i][j]);
      }
    }
    const float* bi_p = dir ? bihb : bihf;
    const float* bh_p = dir ? bhhb : bhhf;
    float bias[8];
#pragma unroll
    for (int j = 0; j < 8; ++j) { int n = n0 + tx*8 + j; bias[j] = bi_p[n] + bh_p[n]; }
    const int mb = m0 + ty * 8;
    const int tt = mb >> 5, bb = mb & 31;
#pragma unroll
    for (int j = 0; j < 8; ++j) {
      int n = n0 + tx*8 + j;
      float* dst = &xproj[((((size_t)dir*512 + tt)*1024) + n)*32 + bb];
      vf4 o0, o1;
      o0[0] = acc[0][j]+bias[j]; o0[1] = acc[1][j]+bias[j];
      o0[2] = acc[2][j]+bias[j]; o0[3] = acc[3][j]+bias[j];
      o1[0] = acc[4][j]+bias[j]; o1[1] = acc[5][j]+bias[j];
      o1[2] = acc[6][j]+bias[j]; o1[3] = acc[7][j]+bias[j];
      asm volatile(
        "global_store_dwordx4 %0, %2, off sc0 sc1\n\t"
        "global_store_dwordx4 %1, %3, off sc0 sc1"
        :: "v"(dst), "v"(dst + 4), "v"(o0), "v"(o1) : "memory");
    }
    asm volatile("s_waitcnt vmcnt(0)" ::: "memory");
    __syncthreads();
    if (tid == 0) {
      float* fp = hist + (size_t)dir * 1024 + (size_t)mt * 8 + y;
      const float z = 0.f;
      asm volatile("global_store_dword %0, %1, off sc0 sc1"
                   :: "v"(fp), "v"(z) : "memory");
    }
    return;
  }

  if (bid >= 2112) {
    // ================= feats path =================
    const int f = bid - 2112;                 // 0..511
    const int t = (f & 1) ? (256 + (f >> 1)) : (255 - (f >> 1));
    float* hlds = smem;                       // [32][258] per pass (8256 f)
    const float* sF = hist + ((size_t)0*513 + (t + 1)) * 8192;
    const float* sB = hist + ((size_t)1*513 + (512 - t)) * 8192;
    {
      const int p = tid & 31;
      const float* pp = (((tid >> 5) & 1) ? sB : sF) + 32 * p;
      while (true) {
        float v;
        asm volatile("global_load_dword %0, %1, off sc0 sc1\n\ts_waitcnt vmcnt(0)"
                     : "=&v"(v) : "v"(pp) : "memory");
        int bad = (__float_as_uint(v) == SENTU) ? 1 : 0;
        if (!__any(bad)) break;
        __builtin_amdgcn_s_sleep(64);
      }
    }
    const int b = tid >> 3, ks = tid & 7;
    float accv[3];
    for (int dir2 = 0; dir2 < 2; ++dir2) {
      const float* sp = (dir2 ? sB : sF) + (size_t)tid * 4;
      vf4 v[8];
      while (true) {                          // bulk load + full verify
        asm volatile(
          "global_load_dwordx4 %0, %8, off sc0 sc1\n\t"
          "global_load_dwordx4 %1, %9, off sc0 sc1\n\t"
          "global_load_dwordx4 %2, %10, off sc0 sc1\n\t"
          "global_load_dwordx4 %3, %11, off sc0 sc1\n\t"
          "global_load_dwordx4 %4, %12, off sc0 sc1\n\t"
          "global_load_dwordx4 %5, %13, off sc0 sc1\n\t"
          "global_load_dwordx4 %6, %14, off sc0 sc1\n\t"
          "global_load_dwordx4 %7, %15, off sc0 sc1\n\t"
          "s_waitcnt vmcnt(0)"
          : "=&v"(v[0]), "=&v"(v[1]), "=&v"(v[2]), "=&v"(v[3]),
            "=&v"(v[4]), "=&v"(v[5]), "=&v"(v[6]), "=&v"(v[7])
          : "v"(sp), "v"(sp+1024), "v"(sp+2048), "v"(sp+3072),
            "v"(sp+4096), "v"(sp+5120), "v"(sp+6144), "v"(sp+7168)
          : "memory");
        unsigned z = 0xFFFFFFFFu;
#pragma unroll
        for (int q = 0; q < 8; ++q)
#pragma unroll
          for (int bl = 0; bl < 4; ++bl)
            z = um(z, __float_as_uint(v[q][bl]) ^ SENTU);
        if (z) break;
        __builtin_amdgcn_s_sleep(16);
      }
#pragma unroll
      for (int q = 0; q < 8; ++q)
#pragma unroll
        for (int bl = 0; bl < 4; ++bl)
          hlds[(4*q + bl)*258 + tid] = v[q][bl];   // row b=4q+bl, col j=tid
      __syncthreads();
#pragma unroll
      for (int kt = 0; kt < 3; ++kt) {
        const int k = kt * 8 + ks;
        if (dir2 == 0) accv[kt] = bout[k];
        const float* wr = wout + (size_t)k * 512 + dir2 * 256;
        float a = accv[kt];
#pragma unroll 8
        for (int kk = 0; kk < 256; kk += 4) {
          float4 h4 = *(const float4*)&hlds[b * 258 + kk];
          float4 w4 = *(const float4*)&wr[kk];
          a += h4.x*w4.x + h4.y*w4.y + h4.z*w4.z + h4.w*w4.w;
        }
        accv[kt] = a;
      }
      __syncthreads();                        // before pass-2 overwrites hlds
    }
#pragma unroll
    for (int kt = 0; kt < 3; ++kt)
      feats[((size_t)t * 32 + b) * 24 + kt * 8 + ks] = accv[kt];
    return;
  }

  // ================= LSTM path (R5-verified protocol) =================
  float* hl = smem + 4352;                   // 8192 f
  const int dir = bid >> 5;
  const int slice = bid & 31;
  const int rowg = tid >> 5;           // 0..7 => j_local
  const int bgrp = (tid >> 3) & 3;     // 0..3
  const int kgrp = tid & 7;            // 0..7
  const int jg = slice * 8 + rowg;     // 0..255
  const float* __restrict__ W = dir ? whhb : whhf;

  // weights -> registers: w2[gate][kk2] covers k = kgrp*32 + 2*kk2 (+1)
  float2 w2[4][16];
#pragma unroll
  for (int g = 0; g < 4; ++g)
#pragma unroll
    for (int kk2 = 0; kk2 < 16; ++kk2)
      w2[g][kk2] = *(const float2*)&W[(size_t)(g*256 + jg)*256 + kgrp*32 + 2*kk2];

  // cell state (redundant across kgrp lanes)
  float cc[8];
#pragma unroll
  for (int bi = 0; bi < 8; ++bi)
    cc[bi] = c0[(size_t)(dir*32 + bgrp*8 + bi)*256 + jg];

  const int kk = tid & 31;
  const int base_col = tid & ~31;
  const int kw4 = 4*((tid >> 5) & 7);
  const int rot = (4*kgrp + 2*bgrp) & 31;
  float* const histd = hist + (size_t)dir * 513 * 8192;
  float hnew[8];

  for (int s = 0; s < 512; ++s) {
    const int t = dir ? (511 - s) : s;

    // (a) obtain h input: column j = tid, all 32 b
    vf4 hv[8];
    if (s == 0) {
#pragma unroll
      for (int q = 0; q < 8; ++q)
#pragma unroll
        for (int bl = 0; bl < 4; ++bl)
          hv[q][bl] = h0[(size_t)(dir*32 + 4*q + bl)*256 + tid];
    } else {
      const float* sp = histd + (size_t)s*8192 + (size_t)tid*4;
      const float* p0 = sp;
      const float* p1 = sp + 1024;
      const float* p2 = sp + 2048;
      const float* p3 = sp + 3072;
      const float* p4 = sp + 4096;
      const float* p5 = sp + 5120;
      const float* p6 = sp + 6144;
      const float* p7 = sp + 7168;
      // phase 1: spin on chunk 7 only (small footprint, low MALL traffic)
      while (true) {
        asm volatile(
          "global_load_dwordx4 %0, %1, off sc0 sc1\n\t"
          "s_waitcnt vmcnt(0)"
          : "=&v"(hv[7]) : "v"(p7) : "memory");
        unsigned z = 0xFFFFFFFFu;
#pragma unroll
        for (int bl = 0; bl < 4; ++bl)
          z = um(z, __float_as_uint(hv[7][bl]) ^ SENTU);
        if (z) break;
        __builtin_amdgcn_s_sleep(1);
      }
      // phase 2: bulk load chunks 0..6, verify all 28 words (usually 1 iter)
      while (true) {
        asm volatile(
          "global_load_dwordx4 %0, %7, off sc0 sc1\n\t"
          "global_load_dwordx4 %1, %8, off sc0 sc1\n\t"
          "global_load_dwordx4 %2, %9, off sc0 sc1\n\t"
          "global_load_dwordx4 %3, %10, off sc0 sc1\n\t"
          "global_load_dwordx4 %4, %11, off sc0 sc1\n\t"
          "global_load_dwordx4 %5, %12, off sc0 sc1\n\t"
          "global_load_dwordx4 %6, %13, off sc0 sc1\n\t"
          "s_waitcnt vmcnt(0)"
          : "=&v"(hv[0]), "=&v"(hv[1]), "=&v"(hv[2]), "=&v"(hv[3]),
            "=&v"(hv[4]), "=&v"(hv[5]), "=&v"(hv[6])
          : "v"(p0), "v"(p1), "v"(p2), "v"(p3),
            "v"(p4), "v"(p5), "v"(p6)
          : "memory");
        unsigned z = 0xFFFFFFFFu;
#pragma unroll
        for (int q = 0; q < 7; ++q)
#pragma unroll
          for (int bl = 0; bl < 4; ++bl)
            z = um(z, __float_as_uint(hv[q][bl]) ^ SENTU);
        if (z) break;
        __builtin_amdgcn_s_sleep(1);
      }
    }

    // (b) flag-gate (once per 4 steps) + xproj prefetch for THIS step, issued
    // AFTER the poll so the poll's vmcnt(0) never drains it; consumed after
    // the FMA block (~1.2us cover). Plain cached loads (flag => MALL truth).
    float xpr[4][8];
    if (kgrp == 0) {
      if ((t & 3) == (dir ? 3 : 0)) {
        const float* fp = hist + (size_t)dir*1024 + (size_t)(t >> 2)*8;
        while (true) {
          vf4 f0, f1;
          asm volatile(
            "global_load_dwordx4 %0, %2, off sc0 sc1\n\t"
            "global_load_dwordx4 %1, %3, off sc0 sc1\n\t"
            "s_waitcnt vmcnt(0)"
            : "=&v"(f0), "=&v"(f1) : "v"(fp), "v"(fp + 4) : "memory");
          unsigned bad = 0u;
#pragma unroll
          for (int l = 0; l < 4; ++l) {
            bad |= (__float_as_uint(f0[l]) == SENTU) ? 1u : 0u;
            bad |= (__float_as_uint(f1[l]) == SENTU) ? 1u : 0u;
          }
          if (!bad) break;
          __builtin_amdgcn_s_sleep(2);
        }
      }
#pragma unroll
      for (int g = 0; g < 4; ++g) {
        const float* xp = &xproj[((((size_t)dir*512 + t)*1024) + g*256 + jg)*32 + bgrp*8];
        float4 x0 = *(const float4*)xp;
        float4 x1 = *(const float4*)(xp + 4);
        xpr[g][0]=x0.x; xpr[g][1]=x0.y; xpr[g][2]=x0.z; xpr[g][3]=x0.w;
        xpr[g][4]=x1.x; xpr[g][5]=x1.y; xpr[g][6]=x1.z; xpr[g][7]=x1.w;
      }
    }

    // (c) scatter to LDS with rotation swizzle (identical hl contents as verified)
#pragma unroll
    for (int q = 0; q < 8; ++q) {
      const int rwq = (kw4 + 2*((q >> 1) & 3)) & 31;
      const int col = base_col + ((kk + rwq) & 31);
#pragma unroll
      for (int bl = 0; bl < 4; ++bl)
        hl[(4*q + bl)*256 + col] = hv[q][bl];
    }
    BARRIER_LGKM();

    // (d) gates partial sums over our 32-k slice
    float acc[4][8];
#pragma unroll
    for (int g = 0; g < 4; ++g)
#pragma unroll
      for (int bi = 0; bi < 8; ++bi) acc[g][bi] = 0.f;

    const int hbase = kgrp * 32;
#pragma unroll
    for (int kk2 = 0; kk2 < 16; ++kk2) {
      const int idx = hbase + ((2*kk2 + rot) & 31);
      float2 h2[8];
#pragma unroll
      for (int bi = 0; bi < 8; ++bi)
        h2[bi] = *(const float2*)&hl[(bgrp*8 + bi)*256 + idx];
#pragma unroll
      for (int g = 0; g < 4; ++g)
#pragma unroll
        for (int bi = 0; bi < 8; ++bi) {
          acc[g][bi] = fmaf(w2[g][kk2].x, h2[bi].x, acc[g][bi]);
          acc[g][bi] = fmaf(w2[g][kk2].y, h2[bi].y, acc[g][bi]);
        }
    }

    // (e) xproj term once (kgrp==0), then butterfly-reduce over the 8 kgrp lanes
    if (kgrp == 0) {
#pragma unroll
      for (int g = 0; g < 4; ++g)
#pragma unroll
        for (int bi = 0; bi < 8; ++bi) acc[g][bi] += xpr[g][bi];
    }
#pragma unroll
    for (int g = 0; g < 4; ++g)
#pragma unroll
      for (int bi = 0; bi < 8; ++bi) {
        float v = acc[g][bi];
        v += __shfl_xor(v, 1, 64);
        v += __shfl_xor(v, 2, 64);
        v += __shfl_xor(v, 4, 64);
        acc[g][bi] = v;
      }

    // (f) LSTM cell update (PyTorch gate order i,f,g,o)
#pragma unroll
    for (int bi = 0; bi < 8; ++bi) {
      float ig = fsig(acc[0][bi]);
      float fg = fsig(acc[1][bi]);
      float gg = ftanh(acc[2][bi]);
      float og = fsig(acc[3][bi]);
      cc[bi] = fg * cc[bi] + ig * gg;
      hnew[bi] = og * ftanh(cc[bi]);
    }

    // (g) publish h into slot s+1 immediately (fire & forget; rides across the
    // barrier below; next poll's vmcnt(0) retires it before hnew is rewritten)
    if (kgrp == 0) {
      float* dp  = histd + (size_t)(s + 1)*8192 + ((size_t)(2*bgrp)*256 + jg)*4;
      float* dp2 = dp + 1024;
      vf4 s0; s0.x = hnew[0]; s0.y = hnew[1]; s0.z = hnew[2]; s0.w = hnew[3];
      vf4 s1; s1.x = hnew[4]; s1.y = hnew[5]; s1.z = hnew[6]; s1.w = hnew[7];
      asm volatile(
        "global_store_dwordx4 %0, %2, off sc0 sc1\n\t"
        "global_store_dwordx4 %1, %3, off sc0 sc1"
        :: "v"(dp), "v"(dp2), "v"(s0), "v"(s1) : "memory");
    }

    BARRIER_LGKM();   // protect hl before next scatter (no vmcnt drain)
  }
}

// ---------------- K5: Viterbi + backtrace, one wave per batch element ----------------
// R7: fv stays in registers (lane k holds fv[k]); the all-to-all broadcast uses
// 24 compile-time v_readlane_b32 (uniform) instead of LDS write + barrier +
// float4 LDS read + barrier per step. Comparisons use bit-identical values
// (fv[pv] + trr[pv], same pairing), 4-chain ILP max preserves first-max.
__global__ __launch_bounds__(64) void k_viterbi(
    const float* __restrict__ feats, const float* __restrict__ trans,
    float* __restrict__ out)
{
  const int b = blockIdx.x;      // 0..31
  const int lane = threadIdx.x;  // 0..63 ; active tag lane if <24
  __shared__ float fvfin[32];
  __shared__ float pathb[512];
  __shared__ unsigned char bcol[512 * 24];
  float trr[24];
#pragma unroll
  for (int pv = 0; pv < 24; ++pv) trr[pv] = 0.f;
  if (lane < 24) {
#pragma unroll
    for (int pv = 0; pv < 24; ++pv) trr[pv] = trans[lane * 24 + pv];
  }
  float fv = (lane == START_TAG) ? 0.f : NEGV;   // lane k holds fv[k]
  float fcur = (lane < 24) ? feats[b * 24 + lane] : 0.f;
  for (int t = 0; t < 512; ++t) {
    float fnext = (t < 511 && lane < 24) ? feats[(size_t)(t + 1) * 768 + b * 24 + lane] : 0.f;
    // broadcast fv[0..23] to all lanes (uniform SGPR values)
    float s[24];
#pragma unroll
    for (int pv = 0; pv < 24; ++pv) s[pv] = rdlane(fv, pv);
    // 4 independent 6-chains (ILP), merge earlier-chain-wins-ties
    float c0v = -3.4e38f, c1v = -3.4e38f, c2v = -3.4e38f, c3v = -3.4e38f;
    int   c0i = 0, c1i = 6, c2i = 12, c3i = 18;
#pragma unroll
    for (int j = 0; j < 6; ++j) {
      float v0 = s[j]      + trr[j];
      float v1 = s[6 + j]  + trr[6 + j];
      float v2 = s[12 + j] + trr[12 + j];
      float v3 = s[18 + j] + trr[18 + j];
      if (v0 > c0v) { c0v = v0; c0i = j; }
      if (v1 > c1v) { c1v = v1; c1i = 6 + j; }
      if (v2 > c2v) { c2v = v2; c2i = 12 + j; }
      if (v3 > c3v) { c3v = v3; c3i = 18 + j; }
    }
    if (c1v > c0v) { c0v = c1v; c0i = c1i; }
    if (c3v > c2v) { c2v = c3v; c2i = c3i; }
    float best = c0v; int bp = c0i;
    if (c2v > best) { best = c2v; bp = c2i; }
    if (lane < 24) bcol[t * 24 + lane] = (unsigned char)bp;
    fv = best + fcur;          // lanes >=24 compute garbage; never read
    fcur = fnext;
  }
  if (lane < 32) fvfin[lane] = (lane < 24) ? fv : NEGV;
  __syncthreads();             // drain bcol/fvfin LDS writes for lane0
  if (lane == 0) {
    float best = -3.4e38f; int bt = 0;
#pragma unroll
    for (int kk2 = 0; kk2 < 24; ++kk2) {
      float v = fvfin[kk2] + trans[STOP_TAG * 24 + kk2];
      if (v > best) { best = v; bt = kk2; }
    }
    out[b] = best;
    pathb[511] = (float)bt;
    int tag = bt;
    for (int t = 511; t >= 1; --t) {
      tag = bcol[t * 24 + tag];
      pathb[t - 1] = (float)tag;
    }
  }
  __syncthreads();
#pragma unroll
  for (int it = 0; it < 8; ++it)
    out[32 + (size_t)b * 512 + it * 64 + lane] = pathb[it * 64 + lane];
}

// ---------------- launch ----------------
extern "C" void kernel_launch(void* const* d_in, const int* in_sizes, int n_in,
                              void* d_out, int out_size, void* d_ws, size_t ws_size,
                              hipStream_t stream) {
  (void)in_sizes; (void)n_in; (void)out_size; (void)ws_size;
  const int*   sent = (const int*)d_in[0];
  const float* emb  = (const float*)d_in[1];
  const float* wihf = (const float*)d_in[2];
  const float* whhf = (const float*)d_in[3];
  const float* bihf = (const float*)d_in[4];
  const float* bhhf = (const float*)d_in[5];
  const float* wihb = (const float*)d_in[6];
  const float* whhb = (const float*)d_in[7];
  const float* bihb = (const float*)d_in[8];
  const float* bhhb = (const float*)d_in[9];
  const float* wout = (const float*)d_in[10];
  const float* bout = (const float*)d_in[11];
  const float* trans= (const float*)d_in[12];
  const float* h0   = (const float*)d_in[13];
  const float* c0   = (const float*)d_in[14];

  float* ws     = (float*)d_ws;
  float* xproj  = ws + XPROJ_OFF;
  float* feats  = ws + FEATS_OFF;
  float* hist   = ws + HIST_OFF;

  // sentinel-fill hist only (33.6 MB; includes slot-0 flag region of both dirs)
  const int n4 = (int)(HIST_ELEMS / 4);
  k_fill<<<(n4 + 255) / 256, 256, 0, stream>>>(hist, n4);
  // fused dispatch: 64 LSTM blocks (resident first), 2048 GEMM blocks,
  // 512 feats blocks (dispatched last, center-out readiness order).
  k_main<<<2624, 256, 32768, stream>>>(sent, emb, wihf, wihb,
                                       bihf, bhhf, bihb, bhhb,
                                       whhf, whhb, h0, c0,
                                       wout, bout, xproj, feats, hist);
  k_viterbi<<<32, 64, 0, stream>>>(feats, trans, (float*)d_out);
}